// Round 10
// baseline (242.549 us; speedup 1.0000x reference)
//
#include <hip/hip_runtime.h>
#include <hip/hip_bf16.h>
#include <stdint.h>

#define H       2048
#define LOGH    11
#define T_TOK   4096
#define NEXP    8
#define NATOM   64
#define NS      16384

typedef short bf16x8 __attribute__((ext_vector_type(8)));
typedef float f32x4  __attribute__((ext_vector_type(4)));

__device__ __forceinline__ unsigned short f2bf(float f) {
  union { float f; unsigned u; } c;
  c.f = f;
  c.u += 0x7fff + ((c.u >> 16) & 1);
  return (unsigned short)(c.u >> 16);
}

// ---------------- prep: gate (wave/token) + x->bf16 fused; separate blocks cvt W ----------------
__global__ __launch_bounds__(256) void prep_kernel(
    const float* __restrict__ x, const float* __restrict__ gate_w,
    const float* __restrict__ W, unsigned short* __restrict__ xb,
    unsigned short* __restrict__ wb, float4* __restrict__ tokInfo) {
  const int b = blockIdx.x;
  if (b >= T_TOK / 4) {
    const int wblk = b - T_TOK / 4;
    const float4* src = reinterpret_cast<const float4*>(W);
#pragma unroll
    for (int p = 0; p < 8; ++p) {
      const int i = (wblk + p * 512) * 256 + threadIdx.x;
      float4 v = src[i];
      ushort4 o;
      o.x = f2bf(v.x); o.y = f2bf(v.y); o.z = f2bf(v.z); o.w = f2bf(v.w);
      *reinterpret_cast<ushort4*>(wb + (size_t)i * 4) = o;
    }
    return;
  }
  const int wv = threadIdx.x >> 6;
  const int lane = threadIdx.x & 63;
  const int t = b * 4 + wv;
  const float4* xr = reinterpret_cast<const float4*>(x + (size_t)t * H);
  unsigned short* xbr = xb + (size_t)t * H;

  float accs[NEXP];
#pragma unroll
  for (int e = 0; e < NEXP; ++e) accs[e] = 0.f;
#pragma unroll
  for (int it = 0; it < 8; ++it) {
    const int j4 = it * 64 + lane;
    float4 xv = xr[j4];
    ushort4 o;
    o.x = f2bf(xv.x); o.y = f2bf(xv.y); o.z = f2bf(xv.z); o.w = f2bf(xv.w);
    *reinterpret_cast<ushort4*>(xbr + (size_t)j4 * 4) = o;
#pragma unroll
    for (int e = 0; e < NEXP; ++e) {
      float4 gv = reinterpret_cast<const float4*>(gate_w + (size_t)e * H)[j4];
      accs[e] = fmaf(xv.x, gv.x, accs[e]);
      accs[e] = fmaf(xv.y, gv.y, accs[e]);
      accs[e] = fmaf(xv.z, gv.z, accs[e]);
      accs[e] = fmaf(xv.w, gv.w, accs[e]);
    }
  }
#pragma unroll
  for (int e = 0; e < NEXP; ++e) {
    float v = accs[e];
#pragma unroll
    for (int off = 32; off > 0; off >>= 1) v += __shfl_down(v, off);
    accs[e] = v;
  }
  if (lane == 0) {
    float lg[NEXP];
#pragma unroll
    for (int e = 0; e < NEXP; ++e) lg[e] = fminf(fmaxf(accs[e], -50.f), 50.f);
    int e0 = 0; float w0 = lg[0];
#pragma unroll
    for (int e = 1; e < NEXP; ++e) { if (lg[e] > w0) { w0 = lg[e]; e0 = e; } }
    int e1 = -1; float w1 = -3.4e38f;
#pragma unroll
    for (int e = 0; e < NEXP; ++e) {
      if (e == e0) continue;
      if (lg[e] > w1) { w1 = lg[e]; e1 = e; }
    }
    const float r1 = expf(w1 - w0);  // <= 1
    float4 ti;
    ti.x = 1.f / (1.f + r1);
    ti.y = r1 / (1.f + r1);
    ti.z = __int_as_float(e0);
    ti.w = __int_as_float(e1);
    tokInfo[t] = ti;
  }
}

// ---------------- sorted layout helpers ----------------
__device__ __forceinline__ int sortedFlat(int pos) {
  const int l = pos >> 7, k = pos & 127;
  return ((k >> 2) << 9) | (l << 2) | (k & 3);
}

// ---------------- build row-sorted element list + inverse perm + expert softmax probs ----------------
__global__ __launch_bounds__(1024) void build_sort_kernel(
    const int* __restrict__ mask_idx, const float* __restrict__ eaw,
    int* __restrict__ elemT, int* __restrict__ posOfS, float* __restrict__ pbuf) {
  __shared__ int hist[H];
  __shared__ int base[H];
  __shared__ int wsum[16];
  __shared__ int wexc[16];
  const int tid = threadIdx.x;

  if (tid < NEXP) {
    float v[NATOM];
#pragma unroll
    for (int a = 0; a < NATOM; ++a) v[a] = eaw[tid * NATOM + a];
    float m = v[0];
#pragma unroll
    for (int a = 1; a < NATOM; ++a) m = fmaxf(m, v[a]);
    float ssum = 0.f;
#pragma unroll
    for (int a = 0; a < NATOM; ++a) { v[a] = expf(v[a] - m); ssum += v[a]; }
    const float inv = 1.f / ssum;
#pragma unroll
    for (int a = 0; a < NATOM; ++a) pbuf[tid * NATOM + a] = v[a] * inv;
  }

  hist[tid] = 0;
  hist[tid + 1024] = 0;
  __syncthreads();
  for (int s = tid; s < NS; s += 1024) {
    int r = mask_idx[s] >> LOGH;
    atomicAdd(&hist[r], 1);
  }
  __syncthreads();
  int a = hist[2 * tid], b = hist[2 * tid + 1];
  int ps = a + b;
  const int lane = tid & 63, wid = tid >> 6;
#pragma unroll
  for (int off = 1; off < 64; off <<= 1) {
    int n = __shfl_up(ps, off);
    if (lane >= off) ps += n;
  }
  if (lane == 63) wsum[wid] = ps;
  __syncthreads();
  if (tid == 0) {
    int run = 0;
    for (int w = 0; w < 16; ++w) { wexc[w] = run; run += wsum[w]; }
  }
  __syncthreads();
  int ex = wexc[wid] + ps - (a + b);
  base[2 * tid] = ex;
  base[2 * tid + 1] = ex + a;
  __syncthreads();
  for (int s = tid; s < NS; s += 1024) {
    int m = mask_idx[s];
    int r = m >> LOGH, c = m & (H - 1);
    int pos = atomicAdd(&base[r], 1);
    const int fl = sortedFlat(pos);
    elemT[fl] = (r << LOGH) | c;
    posOfS[s] = fl;
  }
}

// ---------------- weighted v2: s-major, all 8 experts/thread, direct write to sorted layout ----------------
__global__ __launch_bounds__(256) void weighted_kernel(
    const float* __restrict__ pbuf, const float* __restrict__ atoms,
    const float* __restrict__ importance, const int* __restrict__ posOfS,
    float* __restrict__ wSortedT) {
  __shared__ float p[NEXP][NATOM];  // 2 KB
  const int tid = threadIdx.x;
#pragma unroll
  for (int i = tid; i < NEXP * NATOM; i += 256) (&p[0][0])[i] = pbuf[i];
  __syncthreads();

  const int s = blockIdx.x * 256 + tid;
  const float* as = atoms + s;

  float acc[NEXP];
#pragma unroll
  for (int e = 0; e < NEXP; ++e) acc[e] = 0.f;

#pragma unroll
  for (int ab = 0; ab < 8; ++ab) {
    float v[8];
#pragma unroll
    for (int j = 0; j < 8; ++j) v[j] = as[(size_t)(ab * 8 + j) * NS];
#pragma unroll
    for (int j = 0; j < 8; ++j)
#pragma unroll
      for (int e = 0; e < NEXP; ++e) acc[e] = fmaf(p[e][ab * 8 + j], v[j], acc[e]);
  }

  const int fl = posOfS[s];
#pragma unroll
  for (int e = 0; e < NEXP; ++e) {
    const float imp = importance[(size_t)e * NS + s];
    const float sig = 1.f / (1.f + expf(-imp));
    wSortedT[(size_t)e * NS + fl] = acc[e] * sig;
  }
}

// ---------------- bf16 MFMA GEMM v2: dbuf LDS + counted-drain 2-phase + 2D XCD chunks ----------------
__global__ __launch_bounds__(256) void gemm_kernel(
    const unsigned short* __restrict__ xb, const unsigned short* __restrict__ wb,
    float* __restrict__ out) {
  __shared__ __align__(16) unsigned short aLds[2][128 * 32];  // 2 x 8 KB
  __shared__ __align__(16) unsigned short bLds[2][128 * 32];  // 2 x 8 KB
  const int tid  = threadIdx.x;
  const int wave = tid >> 6;
  const int lane = tid & 63;
  // 2D XCD chunking: xcd gets 8 m-tiles x 8 n-tiles (per-XCD footprint ~8 MB)
  const int bid = blockIdx.x;
  const int xcd = bid & 7;
  const int j   = bid >> 3;  // 0..63
  const int m_t = ((xcd >> 1) << 3) | (j >> 3);   // 0..31
  const int n_t = ((xcd & 1) << 3) | (j & 7);     // 0..15
  const int m0 = m_t * 128;
  const int n0 = n_t * 128;
  const int wr = wave >> 1;
  const int wc = wave & 1;

  f32x4 acc[4][4];
#pragma unroll
  for (int i = 0; i < 4; ++i)
#pragma unroll
    for (int jj = 0; jj < 4; ++jj)
#pragma unroll
      for (int r = 0; r < 4; ++r) acc[i][jj][r] = 0.f;

  // staging: tile 128x32 bf16 = 8 KB; 256 thr x 16B = 4 KB/pass -> 2 passes per matrix.
  // flat = p*256+tid: row = flat>>2, col8 = (flat&3)*8; LDS offset = flat*8 elems
  // (linear per lane: base + lane*16B, as global_load_lds requires)
#define STAGE(buf, k0)                                                          \
  {                                                                             \
    _Pragma("unroll")                                                           \
    for (int p = 0; p < 2; ++p) {                                               \
      const int flat = p * 256 + tid;                                           \
      const int row = flat >> 2;                                                \
      const int c8 = (flat & 3) * 8;                                            \
      __builtin_amdgcn_global_load_lds(                                         \
          (const __attribute__((address_space(1))) unsigned int*)               \
              (xb + (size_t)(m0 + row) * H + (k0) + c8),                        \
          (__attribute__((address_space(3))) unsigned int*)                     \
              (&aLds[buf][flat * 8]), 16, 0, 0);                                \
      __builtin_amdgcn_global_load_lds(                                         \
          (const __attribute__((address_space(1))) unsigned int*)               \
              (wb + (size_t)(n0 + row) * H + (k0) + c8),                        \
          (__attribute__((address_space(3))) unsigned int*)                     \
              (&bLds[buf][flat * 8]), 16, 0, 0);                                \
    }                                                                           \
  }

  // prologue
  STAGE(0, 0)
  asm volatile("s_waitcnt vmcnt(0)" ::: "memory");
  __builtin_amdgcn_s_barrier();
  __builtin_amdgcn_sched_barrier(0);

  const int kc = (lane >> 4) * 8;
  const int ar = wr * 64 + (lane & 15);
  const int br = wc * 64 + (lane & 15);

  for (int kt = 0; kt < 64; ++kt) {
    const int cur = kt & 1;
    if (kt < 63) STAGE(cur ^ 1, (kt + 1) * 32)  // async; flies under MFMA phase

    bf16x8 af[4], bfr[4];
#pragma unroll
    for (int i = 0; i < 4; ++i)
      af[i] = *reinterpret_cast<const bf16x8*>(&aLds[cur][(ar + i * 16) * 32 + kc]);
#pragma unroll
    for (int jj = 0; jj < 4; ++jj)
      bfr[jj] = *reinterpret_cast<const bf16x8*>(&bLds[cur][(br + jj * 16) * 32 + kc]);
#pragma unroll
    for (int i = 0; i < 4; ++i)
#pragma unroll
      for (int jj = 0; jj < 4; ++jj)
        acc[i][jj] = __builtin_amdgcn_mfma_f32_16x16x32_bf16(af[i], bfr[jj], acc[i][jj], 0, 0, 0);

    __builtin_amdgcn_sched_barrier(0);  // pin ds_read/MFMA above the drain
    asm volatile("s_waitcnt vmcnt(0) lgkmcnt(0)" ::: "memory");
    __builtin_amdgcn_s_barrier();
    __builtin_amdgcn_sched_barrier(0);  // keep next iter's ops below the barrier
  }
#undef STAGE

  const int cr = (lane >> 4) * 4;
  const int cc = lane & 15;
#pragma unroll
  for (int i = 0; i < 4; ++i)
#pragma unroll
    for (int jj = 0; jj < 4; ++jj)
#pragma unroll
      for (int r = 0; r < 4; ++r)
        out[(size_t)(m0 + wr * 64 + i * 16 + cr + r) * H + (n0 + wc * 64 + jj * 16 + cc)] =
            acc[i][jj][r];
}

// ---------------- scatter v4b: 128-lane vec4 streams, x row loaded from bf16 xb ----------------
__global__ __launch_bounds__(512) void scatter_kernel(
    const unsigned short* __restrict__ xb, const float* __restrict__ wSortedT,
    const int* __restrict__ elemT, const float4* __restrict__ tokInfo,
    float* __restrict__ out) {
  __shared__ float xrow[4][H];   // 32 KB
  __shared__ float acc[4][H];    // 32 KB
  const int tid  = threadIdx.x;
  const int tk   = tid >> 7;       // token slot 0..3
  const int l    = tid & 127;      // lane within token stream
  const int t0   = blockIdx.x * 4;

  {
    const uint4* xsrc = reinterpret_cast<const uint4*>(xb + (size_t)t0 * H);  // 8 bf16/load
    float4* xdst = reinterpret_cast<float4*>(&xrow[0][0]);
    float4* adst = reinterpret_cast<float4*>(&acc[0][0]);
    float4 z; z.x = z.y = z.z = z.w = 0.f;
#pragma unroll
    for (int i = 0; i < 2; ++i) {
      const int idx = tid + i * 512;     // uint4 index, 1024 total
      uint4 v = xsrc[idx];
      float4 f0, f1;
      f0.x = __uint_as_float(v.x << 16);
      f0.y = __uint_as_float(v.x & 0xffff0000u);
      f0.z = __uint_as_float(v.y << 16);
      f0.w = __uint_as_float(v.y & 0xffff0000u);
      f1.x = __uint_as_float(v.z << 16);
      f1.y = __uint_as_float(v.z & 0xffff0000u);
      f1.z = __uint_as_float(v.w << 16);
      f1.w = __uint_as_float(v.w & 0xffff0000u);
      xdst[idx * 2]     = f0;
      xdst[idx * 2 + 1] = f1;
    }
#pragma unroll
    for (int i = 0; i < 4; ++i) adst[tid + i * 512] = z;
  }
  __syncthreads();

  const int t = t0 + tk;
  const float4 ti = tokInfo[t];
  const float rw0 = ti.x, rw1 = ti.y;
  const int e0 = __float_as_int(ti.z);
  const int e1 = __float_as_int(ti.w);

  const int4*   ev4 = reinterpret_cast<const int4*>(elemT);
  const float4* w04 = reinterpret_cast<const float4*>(wSortedT + (size_t)e0 * NS);
  const float4* w14 = reinterpret_cast<const float4*>(wSortedT + (size_t)e1 * NS);
  float* xw = &xrow[tk][0];
  float* aw = &acc[tk][0];

  float accv = 0.f;
  int curR = -1;
  int flushed = 0;

  int4   ev = ev4[l];
  float4 a  = w04[l];
  float4 b  = w14[l];

#define PROC1(EV, AV, BV, GV)                                     \
  {                                                               \
    const int r = (EV) >> LOGH;                                   \
    const float ct = (GV) * fmaf(rw0, (AV), rw1 * (BV));          \
    if (r != curR) {                                              \
      if (curR >= 0) {                                            \
        if (flushed) aw[curR] = accv;                             \
        else { atomicAdd(&aw[curR], accv); flushed = 1; }         \
      }                                                           \
      curR = r; accv = ct;                                        \
    } else {                                                      \
      accv += ct;                                                 \
    }                                                             \
  }

#pragma unroll 4
  for (int s = 0; s < 32; ++s) {
    const int sn = (s + 1 <= 31) ? s + 1 : 31;
    int4   evN = ev4[sn * 128 + l];
    float4 aN  = w04[sn * 128 + l];
    float4 bN  = w14[sn * 128 + l];
    const float g0 = xw[ev.x & (H - 1)];
    const float g1 = xw[ev.y & (H - 1)];
    const float g2 = xw[ev.z & (H - 1)];
    const float g3 = xw[ev.w & (H - 1)];
    PROC1(ev.x, a.x, b.x, g0)
    PROC1(ev.y, a.y, b.y, g1)
    PROC1(ev.z, a.z, b.z, g2)
    PROC1(ev.w, a.w, b.w, g3)
    ev = evN; a = aN; b = bN;
  }
  atomicAdd(&aw[curR], accv);  // final flush (row may be shared with next lane)
  __syncthreads();
#undef PROC1

  {
    float4* orow = reinterpret_cast<float4*>(out + (size_t)t * H);
    const float4* arow = reinterpret_cast<const float4*>(aw);
#pragma unroll
    for (int i = 0; i < 4; ++i) {
      int idx = l + i * 128;
      float4 o = orow[idx];
      float4 av = arow[idx];
      o.x += av.x; o.y += av.y; o.z += av.z; o.w += av.w;
      orow[idx] = o;
    }
  }
}

extern "C" void kernel_launch(void* const* d_in, const int* in_sizes, int n_in,
                              void* d_out, int out_size, void* d_ws, size_t ws_size,
                              hipStream_t stream) {
  const float* x          = (const float*)d_in[0];
  const float* gate_w     = (const float*)d_in[1];
  const float* W          = (const float*)d_in[2];
  const float* atoms      = (const float*)d_in[3];
  const float* eaw        = (const float*)d_in[4];
  const float* importance = (const float*)d_in[5];
  const int*   mask_idx   = (const int*)d_in[6];
  float* out = (float*)d_out;

  char* ws = (char*)d_ws;
  size_t off = 0;
  unsigned short* xb = (unsigned short*)(ws + off); off += (size_t)T_TOK * H * 2;  // 16 MB
  unsigned short* wb = (unsigned short*)(ws + off); off += (size_t)H * H * 2;      // 8 MB
  float4* tokInfo    = (float4*)(ws + off);         off += (size_t)T_TOK * 16;     // 64 KB
  int* elemT         = (int*)(ws + off);            off += (size_t)NS * 4;         // 64 KB
  int* posOfS        = (int*)(ws + off);            off += (size_t)NS * 4;         // 64 KB
  float* wSortedT    = (float*)(ws + off);          off += (size_t)NEXP * NS * 4;  // 512 KB
  float* pbuf        = (float*)(ws + off);          off += (size_t)NEXP * NATOM * 4;  // 2 KB

  prep_kernel<<<T_TOK / 4 + 512, 256, 0, stream>>>(x, gate_w, W, xb, wb, tokInfo);
  build_sort_kernel<<<1, 1024, 0, stream>>>(mask_idx, eaw, elemT, posOfS, pbuf);
  weighted_kernel<<<NS / 256, 256, 0, stream>>>(pbuf, atoms, importance, posOfS, wSortedT);
  gemm_kernel<<<512, 256, 0, stream>>>(xb, wb, out);
  scatter_kernel<<<T_TOK / 4, 512, 0, stream>>>(xb, wSortedT, elemT, tokInfo, out);
}

// Round 11
// 236.360 us; speedup vs baseline: 1.0262x; 1.0262x over previous
//
#include <hip/hip_runtime.h>
#include <hip/hip_bf16.h>
#include <stdint.h>

#define H       2048
#define LOGH    11
#define T_TOK   4096
#define NEXP    8
#define NATOM   64
#define NS      16384

typedef short bf16x8 __attribute__((ext_vector_type(8)));
typedef float f32x4  __attribute__((ext_vector_type(4)));

__device__ __forceinline__ unsigned short f2bf(float f) {
  union { float f; unsigned u; } c;
  c.f = f;
  c.u += 0x7fff + ((c.u >> 16) & 1);
  return (unsigned short)(c.u >> 16);
}

// ---------------- prep: gate (wave/token) + x->bf16 fused; separate blocks cvt W ----------------
__global__ __launch_bounds__(256) void prep_kernel(
    const float* __restrict__ x, const float* __restrict__ gate_w,
    const float* __restrict__ W, unsigned short* __restrict__ xb,
    unsigned short* __restrict__ wb, float4* __restrict__ tokInfo) {
  const int b = blockIdx.x;
  if (b >= T_TOK / 4) {
    const int wblk = b - T_TOK / 4;
    const float4* src = reinterpret_cast<const float4*>(W);
#pragma unroll
    for (int p = 0; p < 8; ++p) {
      const int i = (wblk + p * 512) * 256 + threadIdx.x;
      float4 v = src[i];
      ushort4 o;
      o.x = f2bf(v.x); o.y = f2bf(v.y); o.z = f2bf(v.z); o.w = f2bf(v.w);
      *reinterpret_cast<ushort4*>(wb + (size_t)i * 4) = o;
    }
    return;
  }
  const int wv = threadIdx.x >> 6;
  const int lane = threadIdx.x & 63;
  const int t = b * 4 + wv;
  const float4* xr = reinterpret_cast<const float4*>(x + (size_t)t * H);
  unsigned short* xbr = xb + (size_t)t * H;

  float accs[NEXP];
#pragma unroll
  for (int e = 0; e < NEXP; ++e) accs[e] = 0.f;
#pragma unroll
  for (int it = 0; it < 8; ++it) {
    const int j4 = it * 64 + lane;
    float4 xv = xr[j4];
    ushort4 o;
    o.x = f2bf(xv.x); o.y = f2bf(xv.y); o.z = f2bf(xv.z); o.w = f2bf(xv.w);
    *reinterpret_cast<ushort4*>(xbr + (size_t)j4 * 4) = o;
#pragma unroll
    for (int e = 0; e < NEXP; ++e) {
      float4 gv = reinterpret_cast<const float4*>(gate_w + (size_t)e * H)[j4];
      accs[e] = fmaf(xv.x, gv.x, accs[e]);
      accs[e] = fmaf(xv.y, gv.y, accs[e]);
      accs[e] = fmaf(xv.z, gv.z, accs[e]);
      accs[e] = fmaf(xv.w, gv.w, accs[e]);
    }
  }
#pragma unroll
  for (int e = 0; e < NEXP; ++e) {
    float v = accs[e];
#pragma unroll
    for (int off = 32; off > 0; off >>= 1) v += __shfl_down(v, off);
    accs[e] = v;
  }
  if (lane == 0) {
    float lg[NEXP];
#pragma unroll
    for (int e = 0; e < NEXP; ++e) lg[e] = fminf(fmaxf(accs[e], -50.f), 50.f);
    int e0 = 0; float w0 = lg[0];
#pragma unroll
    for (int e = 1; e < NEXP; ++e) { if (lg[e] > w0) { w0 = lg[e]; e0 = e; } }
    int e1 = -1; float w1 = -3.4e38f;
#pragma unroll
    for (int e = 0; e < NEXP; ++e) {
      if (e == e0) continue;
      if (lg[e] > w1) { w1 = lg[e]; e1 = e; }
    }
    const float r1 = expf(w1 - w0);  // <= 1
    float4 ti;
    ti.x = 1.f / (1.f + r1);
    ti.y = r1 / (1.f + r1);
    ti.z = __int_as_float(e0);
    ti.w = __int_as_float(e1);
    tokInfo[t] = ti;
  }
}

// ---------------- sorted layout helpers ----------------
__device__ __forceinline__ int sortedFlat(int pos) {
  const int l = pos >> 7, k = pos & 127;
  return ((k >> 2) << 9) | (l << 2) | (k & 3);
}

// ---------------- build row-sorted element list + inverse perm + expert softmax probs ----------------
__global__ __launch_bounds__(1024) void build_sort_kernel(
    const int* __restrict__ mask_idx, const float* __restrict__ eaw,
    int* __restrict__ elemT, int* __restrict__ posOfS, float* __restrict__ pbuf) {
  __shared__ int hist[H];
  __shared__ int base[H];
  __shared__ int wsum[16];
  __shared__ int wexc[16];
  const int tid = threadIdx.x;

  if (tid < NEXP) {
    float v[NATOM];
#pragma unroll
    for (int a = 0; a < NATOM; ++a) v[a] = eaw[tid * NATOM + a];
    float m = v[0];
#pragma unroll
    for (int a = 1; a < NATOM; ++a) m = fmaxf(m, v[a]);
    float ssum = 0.f;
#pragma unroll
    for (int a = 0; a < NATOM; ++a) { v[a] = expf(v[a] - m); ssum += v[a]; }
    const float inv = 1.f / ssum;
#pragma unroll
    for (int a = 0; a < NATOM; ++a) pbuf[tid * NATOM + a] = v[a] * inv;
  }

  hist[tid] = 0;
  hist[tid + 1024] = 0;
  __syncthreads();
  for (int s = tid; s < NS; s += 1024) {
    int r = mask_idx[s] >> LOGH;
    atomicAdd(&hist[r], 1);
  }
  __syncthreads();
  int a = hist[2 * tid], b = hist[2 * tid + 1];
  int ps = a + b;
  const int lane = tid & 63, wid = tid >> 6;
#pragma unroll
  for (int off = 1; off < 64; off <<= 1) {
    int n = __shfl_up(ps, off);
    if (lane >= off) ps += n;
  }
  if (lane == 63) wsum[wid] = ps;
  __syncthreads();
  if (tid == 0) {
    int run = 0;
    for (int w = 0; w < 16; ++w) { wexc[w] = run; run += wsum[w]; }
  }
  __syncthreads();
  int ex = wexc[wid] + ps - (a + b);
  base[2 * tid] = ex;
  base[2 * tid + 1] = ex + a;
  __syncthreads();
  for (int s = tid; s < NS; s += 1024) {
    int m = mask_idx[s];
    int r = m >> LOGH, c = m & (H - 1);
    int pos = atomicAdd(&base[r], 1);
    const int fl = sortedFlat(pos);
    elemT[fl] = (r << LOGH) | c;
    posOfS[s] = fl;
  }
}

// ---------------- weighted v2: s-major, all 8 experts/thread, direct write to sorted layout ----------------
__global__ __launch_bounds__(256) void weighted_kernel(
    const float* __restrict__ pbuf, const float* __restrict__ atoms,
    const float* __restrict__ importance, const int* __restrict__ posOfS,
    float* __restrict__ wSortedT) {
  __shared__ float p[NEXP][NATOM];  // 2 KB
  const int tid = threadIdx.x;
#pragma unroll
  for (int i = tid; i < NEXP * NATOM; i += 256) (&p[0][0])[i] = pbuf[i];
  __syncthreads();

  const int s = blockIdx.x * 256 + tid;
  const float* as = atoms + s;

  float acc[NEXP];
#pragma unroll
  for (int e = 0; e < NEXP; ++e) acc[e] = 0.f;

#pragma unroll
  for (int ab = 0; ab < 8; ++ab) {
    float v[8];
#pragma unroll
    for (int j = 0; j < 8; ++j) v[j] = as[(size_t)(ab * 8 + j) * NS];
#pragma unroll
    for (int j = 0; j < 8; ++j)
#pragma unroll
      for (int e = 0; e < NEXP; ++e) acc[e] = fmaf(p[e][ab * 8 + j], v[j], acc[e]);
  }

  const int fl = posOfS[s];
#pragma unroll
  for (int e = 0; e < NEXP; ++e) {
    const float imp = importance[(size_t)e * NS + s];
    const float sig = 1.f / (1.f + expf(-imp));
    wSortedT[(size_t)e * NS + fl] = acc[e] * sig;
  }
}

// ---------------- bf16 MFMA GEMM v3: depth-3 counted-vmcnt pipeline + LDS XOR-swizzle ----------------
__global__ __launch_bounds__(256) void gemm_kernel(
    const unsigned short* __restrict__ xb, const unsigned short* __restrict__ wb,
    float* __restrict__ out) {
  __shared__ __align__(16) unsigned short aLds[3][128 * 32];  // 3 x 8 KB
  __shared__ __align__(16) unsigned short bLds[3][128 * 32];  // 3 x 8 KB
  const int tid  = threadIdx.x;
  const int wave = tid >> 6;
  const int lane = tid & 63;
  // 2D XCD chunking: xcd gets 8 m-tiles x 8 n-tiles (per-XCD footprint ~8 MB)
  const int bid = blockIdx.x;
  const int xcd = bid & 7;
  const int j   = bid >> 3;  // 0..63
  const int m_t = ((xcd >> 1) << 3) | (j >> 3);   // 0..31
  const int n_t = ((xcd & 1) << 3) | (j & 7);     // 0..15
  const int m0 = m_t * 128;
  const int n0 = n_t * 128;
  const int wr = wave >> 1;
  const int wc = wave & 1;

  f32x4 acc[4][4];
#pragma unroll
  for (int i = 0; i < 4; ++i)
#pragma unroll
    for (int jj = 0; jj < 4; ++jj)
#pragma unroll
      for (int r = 0; r < 4; ++r) acc[i][jj][r] = 0.f;

  // Staging with source-side swizzle (rule #21: LDS dest linear, global src permuted):
  // dest slot flat -> row=flat>>2, destchunk=flat&3; data placed there is logical
  // chunk lc = destchunk ^ ((row>>1)&3). Read side XORs the same swizzle.
#define STAGE(buf, kt_)                                                         \
  {                                                                             \
    _Pragma("unroll")                                                           \
    for (int p = 0; p < 2; ++p) {                                               \
      const int flat = p * 256 + tid;                                           \
      const int row = flat >> 2;                                                \
      const int lc = (flat & 3) ^ ((row >> 1) & 3);                             \
      __builtin_amdgcn_global_load_lds(                                         \
          (const __attribute__((address_space(1))) unsigned int*)               \
              (xb + (size_t)(m0 + row) * H + (kt_) * 32 + lc * 8),              \
          (__attribute__((address_space(3))) unsigned int*)                     \
              (&aLds[buf][flat * 8]), 16, 0, 0);                                \
      __builtin_amdgcn_global_load_lds(                                         \
          (const __attribute__((address_space(1))) unsigned int*)               \
              (wb + (size_t)(n0 + row) * H + (kt_) * 32 + lc * 8),              \
          (__attribute__((address_space(3))) unsigned int*)                     \
              (&bLds[buf][flat * 8]), 16, 0, 0);                                \
    }                                                                           \
  }

  const int kc = (lane >> 4) * 8;
  const int ar = wr * 64 + (lane & 15);
  const int br = wc * 64 + (lane & 15);
  const int kcS = kc ^ ((((lane & 15) >> 1) & 3) << 3);  // swizzled k-offset (row+16 invariant)

  // prologue: stage tiles 0 and 1
  STAGE(0, 0)
  STAGE(1, 1)

  for (int kt = 0; kt < 64; ++kt) {
    const int cur = kt % 3;
    if (kt < 62) { STAGE((kt + 2) % 3, kt + 2) }  // keep 2 tiles in flight
    // counted drain: wait only for tile kt's 4 loads (8 newer stay in flight)
    if (kt < 62)      asm volatile("s_waitcnt vmcnt(8)" ::: "memory");
    else if (kt == 62) asm volatile("s_waitcnt vmcnt(4)" ::: "memory");
    else               asm volatile("s_waitcnt vmcnt(0)" ::: "memory");
    __builtin_amdgcn_s_barrier();          // all waves' portions of tile kt arrived
    __builtin_amdgcn_sched_barrier(0);

    bf16x8 af[4], bfr[4];
#pragma unroll
    for (int i = 0; i < 4; ++i)
      af[i] = *reinterpret_cast<const bf16x8*>(&aLds[cur][(ar + i * 16) * 32 + kcS]);
#pragma unroll
    for (int jj = 0; jj < 4; ++jj)
      bfr[jj] = *reinterpret_cast<const bf16x8*>(&bLds[cur][(br + jj * 16) * 32 + kcS]);
#pragma unroll
    for (int i = 0; i < 4; ++i)
#pragma unroll
      for (int jj = 0; jj < 4; ++jj)
        acc[i][jj] = __builtin_amdgcn_mfma_f32_16x16x32_bf16(af[i], bfr[jj], acc[i][jj], 0, 0, 0);

    __builtin_amdgcn_sched_barrier(0);     // reads+MFMA stay above
    __builtin_amdgcn_s_barrier();          // buf[cur] free for restaging at kt+1
    __builtin_amdgcn_sched_barrier(0);
  }
#undef STAGE

  const int cr = (lane >> 4) * 4;
  const int cc = lane & 15;
#pragma unroll
  for (int i = 0; i < 4; ++i)
#pragma unroll
    for (int jj = 0; jj < 4; ++jj)
#pragma unroll
      for (int r = 0; r < 4; ++r)
        out[(size_t)(m0 + wr * 64 + i * 16 + cr + r) * H + (n0 + wc * 64 + jj * 16 + cc)] =
            acc[i][jj][r];
}

// ---------------- scatter v4b: 128-lane vec4 streams, x row loaded from bf16 xb ----------------
__global__ __launch_bounds__(512) void scatter_kernel(
    const unsigned short* __restrict__ xb, const float* __restrict__ wSortedT,
    const int* __restrict__ elemT, const float4* __restrict__ tokInfo,
    float* __restrict__ out) {
  __shared__ float xrow[4][H];   // 32 KB
  __shared__ float acc[4][H];    // 32 KB
  const int tid  = threadIdx.x;
  const int tk   = tid >> 7;       // token slot 0..3
  const int l    = tid & 127;      // lane within token stream
  const int t0   = blockIdx.x * 4;

  {
    const uint4* xsrc = reinterpret_cast<const uint4*>(xb + (size_t)t0 * H);  // 8 bf16/load
    float4* xdst = reinterpret_cast<float4*>(&xrow[0][0]);
    float4* adst = reinterpret_cast<float4*>(&acc[0][0]);
    float4 z; z.x = z.y = z.z = z.w = 0.f;
#pragma unroll
    for (int i = 0; i < 2; ++i) {
      const int idx = tid + i * 512;     // uint4 index, 1024 total
      uint4 v = xsrc[idx];
      float4 f0, f1;
      f0.x = __uint_as_float(v.x << 16);
      f0.y = __uint_as_float(v.x & 0xffff0000u);
      f0.z = __uint_as_float(v.y << 16);
      f0.w = __uint_as_float(v.y & 0xffff0000u);
      f1.x = __uint_as_float(v.z << 16);
      f1.y = __uint_as_float(v.z & 0xffff0000u);
      f1.z = __uint_as_float(v.w << 16);
      f1.w = __uint_as_float(v.w & 0xffff0000u);
      xdst[idx * 2]     = f0;
      xdst[idx * 2 + 1] = f1;
    }
#pragma unroll
    for (int i = 0; i < 4; ++i) adst[tid + i * 512] = z;
  }
  __syncthreads();

  const int t = t0 + tk;
  const float4 ti = tokInfo[t];
  const float rw0 = ti.x, rw1 = ti.y;
  const int e0 = __float_as_int(ti.z);
  const int e1 = __float_as_int(ti.w);

  const int4*   ev4 = reinterpret_cast<const int4*>(elemT);
  const float4* w04 = reinterpret_cast<const float4*>(wSortedT + (size_t)e0 * NS);
  const float4* w14 = reinterpret_cast<const float4*>(wSortedT + (size_t)e1 * NS);
  float* xw = &xrow[tk][0];
  float* aw = &acc[tk][0];

  float accv = 0.f;
  int curR = -1;
  int flushed = 0;

  int4   ev = ev4[l];
  float4 a  = w04[l];
  float4 b  = w14[l];

#define PROC1(EV, AV, BV, GV)                                     \
  {                                                               \
    const int r = (EV) >> LOGH;                                   \
    const float ct = (GV) * fmaf(rw0, (AV), rw1 * (BV));          \
    if (r != curR) {                                              \
      if (curR >= 0) {                                            \
        if (flushed) aw[curR] = accv;                             \
        else { atomicAdd(&aw[curR], accv); flushed = 1; }         \
      }                                                           \
      curR = r; accv = ct;                                        \
    } else {                                                      \
      accv += ct;                                                 \
    }                                                             \
  }

#pragma unroll 4
  for (int s = 0; s < 32; ++s) {
    const int sn = (s + 1 <= 31) ? s + 1 : 31;
    int4   evN = ev4[sn * 128 + l];
    float4 aN  = w04[sn * 128 + l];
    float4 bN  = w14[sn * 128 + l];
    const float g0 = xw[ev.x & (H - 1)];
    const float g1 = xw[ev.y & (H - 1)];
    const float g2 = xw[ev.z & (H - 1)];
    const float g3 = xw[ev.w & (H - 1)];
    PROC1(ev.x, a.x, b.x, g0)
    PROC1(ev.y, a.y, b.y, g1)
    PROC1(ev.z, a.z, b.z, g2)
    PROC1(ev.w, a.w, b.w, g3)
    ev = evN; a = aN; b = bN;
  }
  atomicAdd(&aw[curR], accv);  // final flush (row may be shared with next lane)
  __syncthreads();
#undef PROC1

  {
    float4* orow = reinterpret_cast<float4*>(out + (size_t)t * H);
    const float4* arow = reinterpret_cast<const float4*>(aw);
#pragma unroll
    for (int i = 0; i < 4; ++i) {
      int idx = l + i * 128;
      float4 o = orow[idx];
      float4 av = arow[idx];
      o.x += av.x; o.y += av.y; o.z += av.z; o.w += av.w;
      orow[idx] = o;
    }
  }
}

extern "C" void kernel_launch(void* const* d_in, const int* in_sizes, int n_in,
                              void* d_out, int out_size, void* d_ws, size_t ws_size,
                              hipStream_t stream) {
  const float* x          = (const float*)d_in[0];
  const float* gate_w     = (const float*)d_in[1];
  const float* W          = (const float*)d_in[2];
  const float* atoms      = (const float*)d_in[3];
  const float* eaw        = (const float*)d_in[4];
  const float* importance = (const float*)d_in[5];
  const int*   mask_idx   = (const int*)d_in[6];
  float* out = (float*)d_out;

  char* ws = (char*)d_ws;
  size_t off = 0;
  unsigned short* xb = (unsigned short*)(ws + off); off += (size_t)T_TOK * H * 2;  // 16 MB
  unsigned short* wb = (unsigned short*)(ws + off); off += (size_t)H * H * 2;      // 8 MB
  float4* tokInfo    = (float4*)(ws + off);         off += (size_t)T_TOK * 16;     // 64 KB
  int* elemT         = (int*)(ws + off);            off += (size_t)NS * 4;         // 64 KB
  int* posOfS        = (int*)(ws + off);            off += (size_t)NS * 4;         // 64 KB
  float* wSortedT    = (float*)(ws + off);          off += (size_t)NEXP * NS * 4;  // 512 KB
  float* pbuf        = (float*)(ws + off);          off += (size_t)NEXP * NATOM * 4;  // 2 KB

  prep_kernel<<<T_TOK / 4 + 512, 256, 0, stream>>>(x, gate_w, W, xb, wb, tokInfo);
  build_sort_kernel<<<1, 1024, 0, stream>>>(mask_idx, eaw, elemT, posOfS, pbuf);
  weighted_kernel<<<NS / 256, 256, 0, stream>>>(pbuf, atoms, importance, posOfS, wSortedT);
  gemm_kernel<<<512, 256, 0, stream>>>(xb, wb, out);
  scatter_kernel<<<T_TOK / 4, 512, 0, stream>>>(xb, wSortedT, elemT, tokInfo, out);
}